// Round 3
// baseline (111.640 us; speedup 1.0000x reference)
//
#include <hip/hip_runtime.h>
#include <stdint.h>

// SpottingLoss: B=2048 batches, N=64 slots, F=19 features.
// Two-phase greedy bipartite matching (lax.scan, length 64 each) then
// permuted YOLO-ish loss summed over ALL axes -> single float output.
//
// Exactness argument (verified absmax 0.0 in rounds 0-2):
//  - alpha in {0.0,1.0}; v,h stay exactly {0.0,1.0}; D2 = D1 * (0/1 factors),
//    so masking D1 (fp32, 1 - |x-p|, bit-identical) by the current
//    column-active bitmask reproduces D2 values bitwise.
//  - jnp.argmax ties -> first index. Row scan uses strict '>' over masked
//    values. Column argmax uses packed key (val_bits<<6 | (63-row)):
//    monotone in val (val>0), larger 63-row == smaller row == first index.
//    All-zero column -> winner row 0, reproduced by key init (val=0,row=0)=63.
//  - Dead rows (v=0) only contribute zeros downstream; early exit when
//    ballot(v)==0: all remaining scan steps are no-ops (E==0).
//  - LDS staging is a pure data-movement change: values read from LDS are
//    the same fp32 bits; D1 = 1-|x-p| computed from identical inputs.
//
// Round-3 change (single mechanism vs 52us baseline): ALL global accesses
// were per-lane strided at 76B (row stride 19 floats) -> each vector load
// touched ~60 distinct cachelines (~60 transactions/instr, ~40 instrs/wave),
// and 8 blocks/CU x 9.7KB working set thrashed the 32KB L1. Theory: that
// transaction amplification + L2/L3 latency is the ~80% stall. Fix: stage
// the whole 9.7KB block (yt + yp rows) into LDS via 10 perfectly-coalesced
// float4 loads (1KB/instr), then read every field (alpha, x, p, loss
// gathers) from LDS. perm-dependent gather becomes an LDS gather
// (addr = perm*19+f, 19 odd -> <=2-way bank aliasing, free).

#define NN 64
#define NF 19
#define NW (NN * NF)   // 1216 floats per (block, tensor)
#define NW4 (NW / 4)   // 304 float4

__global__ __launch_bounds__(64) void spotting_loss_kernel(
    const float* __restrict__ yt, const float* __restrict__ yp,
    float* __restrict__ ws)
{
  const int b = blockIdx.x;
  const int i = threadIdx.x;  // row index == lane (one wave per block)
  const float4* __restrict__ yt4 = (const float4*)(yt + (size_t)b * NW);
  const float4* __restrict__ yp4 = (const float4*)(yp + (size_t)b * NW);

  __shared__ float4 yts4[NW4];
  __shared__ float4 yps4[NW4];
  __shared__ unsigned long long key_sh[NN];
  const float* __restrict__ yts = (const float*)yts4;
  const float* __restrict__ yps = (const float*)yps4;

  // Coalesced staging: 2 x 5 float4 loads, 1KB per instruction.
#pragma unroll
  for (int k = 0; k < 5; ++k) {
    const int idx = i + 64 * k;           // 304 = 4*64 + 48
    if (idx < NW4) {
      yts4[idx] = yt4[idx];
      yps4[idx] = yp4[idx];
    }
  }
  __syncthreads();

  const float alpha = yts[i * NF + 0];
  const float x     = yts[i * NF + 1];

  // D1 row in registers. Per unrolled j, yps[j*19+1] is wave-uniform ->
  // LDS broadcast (free).
  float D1r[NN];
#pragma unroll
  for (int j = 0; j < NN; ++j) {
    D1r[j] = 1.0f - fabsf(x - yps[j * NF + 1]);
  }

  unsigned long long hbits = ~0ull;  // column j active <=> bit j set
  int   perm  = 0;                   // matched column (argmax of zero row -> 0)
  int   jmax  = 0;
  float best  = 0.0f;

  for (int phase = 0; phase < 2; ++phase) {
    // phase 0: v0 = alpha ; phase 1: v0 = 1-alpha (neg rows untouched by ph.0)
    bool vlive  = (phase == 0) ? (alpha > 0.5f) : (alpha < 0.5f);
    bool rescan = vlive;

    for (int it = 0; it < NN; ++it) {
      if (__ballot(vlive) == 0ull) break;  // remaining steps are no-ops

      if (rescan) {
        // first-index argmax over D1 masked by active columns
        const unsigned hlo = (unsigned)hbits;
        const unsigned hhi = (unsigned)(hbits >> 32);
        best = -1.0f; jmax = 0;
#pragma unroll
        for (int j = 0; j < NN; ++j) {
          const unsigned bit = (j < 32) ? ((hlo >> j) & 1u)
                                        : ((hhi >> (j - 32)) & 1u);
          const unsigned msk = 0u - bit;  // 0xFFFFFFFF or 0
          const float t = __uint_as_float(__float_as_uint(D1r[j]) & msk);
          if (t > best) { best = t; jmax = j; }
        }
        rescan = false;
      }

      key_sh[i] = 63ull;  // (val=0, row=0) baseline: zero column -> winner 0
      __syncthreads();

      if (vlive && best > 0.0f) {
        const unsigned long long key =
            (((unsigned long long)__float_as_uint(best)) << 6) |
            (unsigned long long)(63 - i);
        atomicMax(&key_sh[jmax], key);
      }
      __syncthreads();

      // column side (lane i == column i): any positive write <=> one match
      const unsigned long long kc = key_sh[i];
      const bool colkill = (kc >> 6) != 0ull;
      const unsigned long long killed = __ballot(colkill);

      if (vlive) {
        const unsigned long long kw = key_sh[jmax];
        const int winner = 63 - (int)(kw & 63ull);
        if (winner == i) {            // mutual match: Permut[i][jmax] = 1
          perm = jmax;
          vlive = false;
        } else if ((killed >> jmax) & 1ull) {
          rescan = true;              // favorite column taken by another row
        }
      }
      hbits &= ~killed;
      __syncthreads();
    }
  }

  // ----- loss (all operands from LDS) -----
  const float* __restrict__ ypr = yps + perm * NF;
  const float* __restrict__ ytr = yts + i * NF;
  const float a  = alpha;
  const float p0 = ypr[0];
  const float p1 = ypr[1];
  const float dx = x - p1;
  const float da = a - p0;
  float s2 = 0.0f;
#pragma unroll
  for (int f = 2; f < NF; ++f) {
    const float d = ytr[f] - ypr[f];
    s2 += d * d;
  }
  float l = a * 5.0f * (dx * dx)
          + a * (da * da)
          + (1.0f - a) * 0.5f * (da * da)
          + a * s2;

  // wave-64 reduction, one plain store per block (no atomic contention)
#pragma unroll
  for (int off = 32; off > 0; off >>= 1) l += __shfl_down(l, off);
  if (i == 0) ws[b] = l;
}

__global__ __launch_bounds__(256) void reduce_ws_kernel(
    const float* __restrict__ ws, float* __restrict__ out, int nb)
{
  const int t = threadIdx.x;
  float s = 0.0f;
  for (int j = t; j < nb; j += 256) s += ws[j];
  __shared__ float part[4];
#pragma unroll
  for (int off = 32; off > 0; off >>= 1) s += __shfl_down(s, off);
  if ((t & 63) == 0) part[t >> 6] = s;
  __syncthreads();
  if (t == 0) out[0] = part[0] + part[1] + part[2] + part[3];
}

extern "C" void kernel_launch(void* const* d_in, const int* in_sizes, int n_in,
                              void* d_out, int out_size, void* d_ws, size_t ws_size,
                              hipStream_t stream) {
  const float* yt = (const float*)d_in[0];
  const float* yp = (const float*)d_in[1];
  float* out = (float*)d_out;
  float* ws  = (float*)d_ws;
  const int B = in_sizes[0] / (NN * NF);

  // harness poisons d_out with 0xAA; out[0] is fully overwritten by the
  // reduce kernel. Zero any additional output slots (none expected).
  if (out_size > 1) {
    hipMemsetAsync(out, 0, sizeof(float) * (size_t)out_size, stream);
  }
  spotting_loss_kernel<<<B, 64, 0, stream>>>(yt, yp, ws);
  reduce_ws_kernel<<<1, 256, 0, stream>>>(ws, out, B);
}